// Round 1
// baseline (14224.484 us; speedup 1.0000x reference)
//
#include <hip/hip_runtime.h>

// PPR power iteration:
//   preds_{t+1} = A_hat @ preds_t + alpha * E, 10 iters, preds_0 = E
// A_hat given as COO (rows, cols, vals), vals pre-scaled by (1-alpha).
// Inputs: d_in[0]=E (N*D f32), d_in[1]=rows (nnz i32), d_in[2]=cols (nnz i32),
//         d_in[3]=vals (nnz f32). Output: N*D f32.

#define ALPHA 0.1f
#define NITER 10
#define DFEAT 128

// dst = ALPHA * E   (vectorized float4)
__global__ void ppr_init_axpy(const float4* __restrict__ E4,
                              float4* __restrict__ dst4, int n4) {
    int i = blockIdx.x * blockDim.x + threadIdx.x;
    if (i < n4) {
        float4 e = E4[i];
        float4 o;
        o.x = ALPHA * e.x;
        o.y = ALPHA * e.y;
        o.z = ALPHA * e.z;
        o.w = ALPHA * e.w;
        dst4[i] = o;
    }
}

// COO scatter-add SpMM: dst[rows[e]] += vals[e] * src[cols[e]]
// 32 threads per edge; each thread handles one float4 (4 features) of 128.
__global__ void ppr_spmm_scatter(const int* __restrict__ rows,
                                 const int* __restrict__ cols,
                                 const float* __restrict__ vals,
                                 const float* __restrict__ src,
                                 float* __restrict__ dst, int nnz) {
    int t = blockIdx.x * blockDim.x + threadIdx.x;
    int e = t >> 5;        // edge index (32 threads/edge)
    int g = t & 31;        // float4 group within the 128 features
    if (e >= nnz) return;

    int r = rows[e];
    int c = cols[e];
    float v = vals[e];

    const float4* s4 = reinterpret_cast<const float4*>(src + (size_t)c * DFEAT);
    float4 x = s4[g];

    float* d = dst + (size_t)r * DFEAT + g * 4;
    atomicAdd(d + 0, v * x.x);
    atomicAdd(d + 1, v * x.y);
    atomicAdd(d + 2, v * x.z);
    atomicAdd(d + 3, v * x.w);
}

extern "C" void kernel_launch(void* const* d_in, const int* in_sizes, int n_in,
                              void* d_out, int out_size, void* d_ws, size_t ws_size,
                              hipStream_t stream) {
    const float* E    = (const float*)d_in[0];
    const int*   rows = (const int*)d_in[1];
    const int*   cols = (const int*)d_in[2];
    const float* vals = (const float*)d_in[3];
    float*       out  = (float*)d_out;
    float*       buf  = (float*)d_ws;   // one N*D f32 ping buffer (25.6 MB)

    const int nd  = in_sizes[0];        // N * D = 6,400,000
    const int nnz = in_sizes[1];        // 850,000
    const int n4  = nd / 4;

    dim3 blk(256);
    dim3 grid_init((n4 + 255) / 256);
    dim3 grid_sc(((size_t)nnz * 32 + 255) / 256);

    // Ping-pong: odd iterations write buf (ws), even iterations write out.
    // Iteration 10 (even) lands in d_out. Source of iteration 1 is E itself.
    const float* src = E;
    for (int it = 1; it <= NITER; ++it) {
        float* dst = (it & 1) ? buf : out;
        ppr_init_axpy<<<grid_init, blk, 0, stream>>>(
            (const float4*)E, (float4*)dst, n4);
        ppr_spmm_scatter<<<grid_sc, blk, 0, stream>>>(
            rows, cols, vals, src, dst, nnz);
        src = dst;
    }
}

// Round 2
// 1066.396 us; speedup vs baseline: 13.3388x; 13.3388x over previous
//
#include <hip/hip_runtime.h>

// PPR power iteration: preds_{t+1} = A_hat @ preds_t + alpha * E, 10 iters.
// A_hat in COO (rows, cols, vals), vals pre-scaled by (1-alpha).
// Strategy: build CSR once per call (amortized over 10 iters), then
// wave-per-row gather SpMM with zero atomics in the iteration loop.

#define ALPHA 0.1f
#define NITER 10
#define DFEAT 128

// ---------------- CSR build ----------------

__global__ void zero_ints(int* __restrict__ p, int n) {
    int i = blockIdx.x * blockDim.x + threadIdx.x;
    if (i < n) p[i] = 0;
}

__global__ void hist_rows(const int* __restrict__ rows, int* __restrict__ counts, int nnz) {
    int e = blockIdx.x * blockDim.x + threadIdx.x;
    if (e < nnz) atomicAdd(&counts[rows[e]], 1);
}

// Single-block exclusive scan: rowptr[i] = sum(counts[0..i-1]), rowptr[N] = nnz.
__global__ void scan_rowptr(const int* __restrict__ counts, int* __restrict__ rowptr, int N) {
    __shared__ int sums[1024];
    const int t = threadIdx.x;
    const int C = (N + 1023) / 1024;
    const int begin = t * C;
    const int end   = min(begin + C, N);

    int local = 0;
    for (int i = begin; i < end; ++i) local += counts[i];
    sums[t] = local;
    __syncthreads();

    // Hillis-Steele inclusive scan over the 1024 chunk sums
    for (int off = 1; off < 1024; off <<= 1) {
        int v = (t >= off) ? sums[t - off] : 0;
        __syncthreads();
        sums[t] += v;
        __syncthreads();
    }

    int run = (t == 0) ? 0 : sums[t - 1];   // exclusive offset for this chunk
    for (int i = begin; i < end; ++i) {
        rowptr[i] = run;
        run += counts[i];
    }
    if (begin < N && end == N) rowptr[N] = run;   // total nnz
}

__global__ void copy_ints(const int* __restrict__ src, int* __restrict__ dst, int n) {
    int i = blockIdx.x * blockDim.x + threadIdx.x;
    if (i < n) dst[i] = src[i];
}

// Permute COO into CSR order; pack (col, val) into int2 for single 8B loads.
__global__ void build_csr(const int* __restrict__ rows, const int* __restrict__ cols,
                          const float* __restrict__ vals, int* __restrict__ offsets,
                          int2* __restrict__ packed, int nnz) {
    int e = blockIdx.x * blockDim.x + threadIdx.x;
    if (e >= nnz) return;
    int r = rows[e];
    int pos = atomicAdd(&offsets[r], 1);
    int2 p;
    p.x = cols[e];
    p.y = __float_as_int(vals[e]);
    packed[pos] = p;
}

// ---------------- SpMM: one wave (64 lanes) per row, float2 per lane ----------------

__global__ void spmm_csr(const int* __restrict__ rowptr, const int2* __restrict__ packed,
                         const float* __restrict__ src, const float* __restrict__ E,
                         float* __restrict__ dst, int N) {
    int w    = (blockIdx.x * blockDim.x + threadIdx.x) >> 6;   // row index
    int lane = threadIdx.x & 63;
    if (w >= N) return;

    int s = rowptr[w];
    int e = rowptr[w + 1];
    size_t base = (size_t)w * DFEAT;

    float2 acc = ((const float2*)(E + base))[lane];
    acc.x *= ALPHA;
    acc.y *= ALPHA;

    for (int i = s; i < e; ++i) {
        int2 p = packed[i];
        float v = __int_as_float(p.y);
        float2 x = ((const float2*)(src + (size_t)p.x * DFEAT))[lane];
        acc.x += v * x.x;
        acc.y += v * x.y;
    }

    ((float2*)(dst + base))[lane] = acc;
}

// ---------------- Fallback (atomic COO) if ws too small for CSR ----------------

__global__ void ppr_init_axpy(const float4* __restrict__ E4, float4* __restrict__ dst4, int n4) {
    int i = blockIdx.x * blockDim.x + threadIdx.x;
    if (i < n4) {
        float4 e = E4[i];
        float4 o = {ALPHA * e.x, ALPHA * e.y, ALPHA * e.z, ALPHA * e.w};
        dst4[i] = o;
    }
}

__global__ void ppr_spmm_scatter(const int* __restrict__ rows, const int* __restrict__ cols,
                                 const float* __restrict__ vals, const float* __restrict__ src,
                                 float* __restrict__ dst, int nnz) {
    int t = blockIdx.x * blockDim.x + threadIdx.x;
    int e = t >> 5;
    int g = t & 31;
    if (e >= nnz) return;
    int r = rows[e];
    int c = cols[e];
    float v = vals[e];
    const float4* s4 = reinterpret_cast<const float4*>(src + (size_t)c * DFEAT);
    float4 x = s4[g];
    float* d = dst + (size_t)r * DFEAT + g * 4;
    atomicAdd(d + 0, v * x.x);
    atomicAdd(d + 1, v * x.y);
    atomicAdd(d + 2, v * x.z);
    atomicAdd(d + 3, v * x.w);
}

extern "C" void kernel_launch(void* const* d_in, const int* in_sizes, int n_in,
                              void* d_out, int out_size, void* d_ws, size_t ws_size,
                              hipStream_t stream) {
    const float* E    = (const float*)d_in[0];
    const int*   rows = (const int*)d_in[1];
    const int*   cols = (const int*)d_in[2];
    const float* vals = (const float*)d_in[3];
    float*       out  = (float*)d_out;

    const int nd  = in_sizes[0];          // N * DFEAT
    const int nnz = in_sizes[1];
    const int N   = nd / DFEAT;

    // ws layout: [ buf: nd f32 ][ rowptr: N+1 i32 ][ offsets: N+1 i32 ][ packed: nnz int2 (8B aligned) ]
    char* ws = (char*)d_ws;
    float* buf    = (float*)ws;
    int*   rowptr = (int*)(ws + (size_t)nd * 4);
    int*   offs   = rowptr + (N + 1);
    size_t packed_off = ((size_t)nd * 4 + (size_t)(N + 1) * 8 + 7) & ~(size_t)7;
    int2*  packed = (int2*)(ws + packed_off);
    size_t needed = packed_off + (size_t)nnz * 8;

    dim3 blk(256);

    if (ws_size >= needed) {
        // ---- CSR build (once per call; amortized over NITER) ----
        dim3 gN(((N + 1) + 255) / 256);
        dim3 gE((nnz + 255) / 256);
        zero_ints<<<gN, blk, 0, stream>>>(offs, N + 1);
        hist_rows<<<gE, blk, 0, stream>>>(rows, offs, nnz);      // offs = counts
        scan_rowptr<<<1, 1024, 0, stream>>>(offs, rowptr, N);
        copy_ints<<<gN, blk, 0, stream>>>(rowptr, offs, N);      // offs = running positions
        build_csr<<<gE, blk, 0, stream>>>(rows, cols, vals, offs, packed, nnz);

        // ---- power iterations: wave-per-row gather SpMM, ping-pong buf/out ----
        dim3 gS(((size_t)N * 64 + 255) / 256);
        const float* src = E;
        for (int it = 1; it <= NITER; ++it) {
            float* dst = (it & 1) ? buf : out;    // NITER even -> final in out
            spmm_csr<<<gS, blk, 0, stream>>>(rowptr, packed, src, E, dst, N);
            src = dst;
        }
    } else {
        // ---- fallback: atomic COO scatter (round-1 version) ----
        const int n4 = nd / 4;
        dim3 gI((n4 + 255) / 256);
        dim3 gA(((size_t)nnz * 32 + 255) / 256);
        const float* src = E;
        for (int it = 1; it <= NITER; ++it) {
            float* dst = (it & 1) ? buf : out;
            ppr_init_axpy<<<gI, blk, 0, stream>>>((const float4*)E, (float4*)dst, n4);
            ppr_spmm_scatter<<<gA, blk, 0, stream>>>(rows, cols, vals, src, dst, nnz);
            src = dst;
        }
    }
}

// Round 3
// 775.942 us; speedup vs baseline: 18.3319x; 1.3743x over previous
//
#include <hip/hip_runtime.h>

// PPR power iteration: preds_{t+1} = A_hat @ preds_t + alpha * E, 10 iters.
// CSR built once per call; wave-per-row gather SpMM, 8-deep software pipeline
// on the edge loop (gather-latency bound -> raise MLP).

#define ALPHA 0.1f
#define NITER 10
#define DFEAT 128

// ---------------- CSR build ----------------

__global__ void zero_ints(int* __restrict__ p, int n) {
    int i = blockIdx.x * blockDim.x + threadIdx.x;
    if (i < n) p[i] = 0;
}

__global__ void hist_rows(const int* __restrict__ rows, int* __restrict__ counts, int nnz) {
    int e = blockIdx.x * blockDim.x + threadIdx.x;
    if (e < nnz) atomicAdd(&counts[rows[e]], 1);
}

// Single-block exclusive scan: rowptr[i] = sum(counts[0..i-1]), rowptr[N] = nnz.
__global__ void scan_rowptr(const int* __restrict__ counts, int* __restrict__ rowptr, int N) {
    __shared__ int sums[1024];
    const int t = threadIdx.x;
    const int C = (N + 1023) / 1024;
    const int begin = t * C;
    const int end   = min(begin + C, N);

    int local = 0;
    for (int i = begin; i < end; ++i) local += counts[i];
    sums[t] = local;
    __syncthreads();

    for (int off = 1; off < 1024; off <<= 1) {
        int v = (t >= off) ? sums[t - off] : 0;
        __syncthreads();
        sums[t] += v;
        __syncthreads();
    }

    int run = (t == 0) ? 0 : sums[t - 1];
    for (int i = begin; i < end; ++i) {
        rowptr[i] = run;
        run += counts[i];
    }
    if (begin < N && end == N) rowptr[N] = run;
}

__global__ void copy_ints(const int* __restrict__ src, int* __restrict__ dst, int n) {
    int i = blockIdx.x * blockDim.x + threadIdx.x;
    if (i < n) dst[i] = src[i];
}

// Permute COO into CSR order; pack (col_byte_offset, val_bits) into int2.
// col pre-scaled to byte offset (col * DFEAT * 4) to shorten the address chain.
__global__ void build_csr(const int* __restrict__ rows, const int* __restrict__ cols,
                          const float* __restrict__ vals, int* __restrict__ offsets,
                          int2* __restrict__ packed, int nnz) {
    int e = blockIdx.x * blockDim.x + threadIdx.x;
    if (e >= nnz) return;
    int r = rows[e];
    int pos = atomicAdd(&offsets[r], 1);
    int2 p;
    p.x = cols[e] * (DFEAT * 4);
    p.y = __float_as_int(vals[e]);
    packed[pos] = p;
}

// ---------------- SpMM: one wave per row, float2/lane, 8-deep pipelined ----------------

#define GATH(k)                                                            \
    int2 p##k = packed[i + k];                                             \
    float2 x##k = *(const float2*)(sp + (size_t)(unsigned)p##k.x + loff);

#define ACC(k)                                                             \
    {   float v = __int_as_float(p##k.y);                                  \
        acc.x += v * x##k.x;                                               \
        acc.y += v * x##k.y; }

__global__ void spmm_csr(const int* __restrict__ rowptr, const int2* __restrict__ packed,
                         const float* __restrict__ src, const float* __restrict__ E,
                         float* __restrict__ dst, int N) {
    int w    = (blockIdx.x * blockDim.x + threadIdx.x) >> 6;
    int lane = threadIdx.x & 63;
    if (w >= N) return;

    int s = rowptr[w];
    int e = rowptr[w + 1];
    size_t base = (size_t)w * DFEAT;
    size_t loff = (size_t)lane * 8;
    const char* sp = (const char*)src;

    float2 acc = ((const float2*)(E + base))[lane];
    acc.x *= ALPHA;
    acc.y *= ALPHA;

    int i = s;
    for (; i + 8 <= e; i += 8) {
        GATH(0) GATH(1) GATH(2) GATH(3) GATH(4) GATH(5) GATH(6) GATH(7)
        ACC(0) ACC(1) ACC(2) ACC(3) ACC(4) ACC(5) ACC(6) ACC(7)
    }
    for (; i + 4 <= e; i += 4) {
        GATH(0) GATH(1) GATH(2) GATH(3)
        ACC(0) ACC(1) ACC(2) ACC(3)
    }
    for (; i < e; ++i) {
        GATH(0)
        ACC(0)
    }

    ((float2*)(dst + base))[lane] = acc;
}

#undef GATH
#undef ACC

// ---------------- Fallback (atomic COO) if ws too small for CSR ----------------

__global__ void ppr_init_axpy(const float4* __restrict__ E4, float4* __restrict__ dst4, int n4) {
    int i = blockIdx.x * blockDim.x + threadIdx.x;
    if (i < n4) {
        float4 e = E4[i];
        float4 o = {ALPHA * e.x, ALPHA * e.y, ALPHA * e.z, ALPHA * e.w};
        dst4[i] = o;
    }
}

__global__ void ppr_spmm_scatter(const int* __restrict__ rows, const int* __restrict__ cols,
                                 const float* __restrict__ vals, const float* __restrict__ src,
                                 float* __restrict__ dst, int nnz) {
    int t = blockIdx.x * blockDim.x + threadIdx.x;
    int e = t >> 5;
    int g = t & 31;
    if (e >= nnz) return;
    int r = rows[e];
    int c = cols[e];
    float v = vals[e];
    const float4* s4 = reinterpret_cast<const float4*>(src + (size_t)c * DFEAT);
    float4 x = s4[g];
    float* d = dst + (size_t)r * DFEAT + g * 4;
    atomicAdd(d + 0, v * x.x);
    atomicAdd(d + 1, v * x.y);
    atomicAdd(d + 2, v * x.z);
    atomicAdd(d + 3, v * x.w);
}

extern "C" void kernel_launch(void* const* d_in, const int* in_sizes, int n_in,
                              void* d_out, int out_size, void* d_ws, size_t ws_size,
                              hipStream_t stream) {
    const float* E    = (const float*)d_in[0];
    const int*   rows = (const int*)d_in[1];
    const int*   cols = (const int*)d_in[2];
    const float* vals = (const float*)d_in[3];
    float*       out  = (float*)d_out;

    const int nd  = in_sizes[0];          // N * DFEAT
    const int nnz = in_sizes[1];
    const int N   = nd / DFEAT;

    // ws layout: [ buf: nd f32 ][ rowptr: N+1 i32 ][ offsets: N+1 i32 ][ packed: nnz int2 ]
    char* ws = (char*)d_ws;
    float* buf    = (float*)ws;
    int*   rowptr = (int*)(ws + (size_t)nd * 4);
    int*   offs   = rowptr + (N + 1);
    size_t packed_off = ((size_t)nd * 4 + (size_t)(N + 1) * 8 + 7) & ~(size_t)7;
    int2*  packed = (int2*)(ws + packed_off);
    size_t needed = packed_off + (size_t)nnz * 8;

    dim3 blk(256);

    if (ws_size >= needed) {
        dim3 gN(((N + 1) + 255) / 256);
        dim3 gE((nnz + 255) / 256);
        zero_ints<<<gN, blk, 0, stream>>>(offs, N + 1);
        hist_rows<<<gE, blk, 0, stream>>>(rows, offs, nnz);
        scan_rowptr<<<1, 1024, 0, stream>>>(offs, rowptr, N);
        copy_ints<<<gN, blk, 0, stream>>>(rowptr, offs, N);
        build_csr<<<gE, blk, 0, stream>>>(rows, cols, vals, offs, packed, nnz);

        dim3 gS(((size_t)N * 64 + 255) / 256);
        const float* src = E;
        for (int it = 1; it <= NITER; ++it) {
            float* dst = (it & 1) ? buf : out;    // NITER even -> final in out
            spmm_csr<<<gS, blk, 0, stream>>>(rowptr, packed, src, E, dst, N);
            src = dst;
        }
    } else {
        const int n4 = nd / 4;
        dim3 gI((n4 + 255) / 256);
        dim3 gA(((size_t)nnz * 32 + 255) / 256);
        const float* src = E;
        for (int it = 1; it <= NITER; ++it) {
            float* dst = (it & 1) ? buf : out;
            ppr_init_axpy<<<gI, blk, 0, stream>>>((const float4*)E, (float4*)dst, n4);
            ppr_spmm_scatter<<<gA, blk, 0, stream>>>(rows, cols, vals, src, dst, nnz);
            src = dst;
        }
    }
}